// Round 1
// baseline (455.295 us; speedup 1.0000x reference)
//
#include <hip/hip_runtime.h>
#include <math.h>

#define B 2
#define V 6
#define C 256
#define Q 900
#define NH 8
#define HD 32
#define RADIUS 2.0f

// keypoints: [0,0,0],[R,0,0],[0,R,0],[-R,0,0]
__device__ __forceinline__ float kpx(int k) { return (k == 1) ? RADIUS : ((k == 3) ? -RADIUS : 0.f); }
__device__ __forceinline__ float kpy(int k) { return (k == 2) ? RADIUS : 0.f; }

__device__ __forceinline__ float tapv(const float* __restrict__ base, float xi, float yi, int W, int H) {
    if (xi < 0.f || xi > (float)(W - 1) || yi < 0.f || yi > (float)(H - 1)) return 0.f;
    int xc = (int)xi, yc = (int)yi;
    return base[yc * W + xc];
}

// One block per (b,q); thread t = channel c. 2 levels x 6 views x 4 keypoints.
__global__ __launch_bounds__(256)
void sampler_kernel(const float* __restrict__ f0, const float* __restrict__ f1,
                    const float* __restrict__ refs, const float* __restrict__ intr,
                    const float* __restrict__ extr, float* __restrict__ sampled)
{
    int b = blockIdx.x / Q, q = blockIdx.x % Q;
    int t = threadIdx.x;
    __shared__ float sx[24], sy[24], sval[24];
    float acc_total = 0.f;

    #pragma unroll
    for (int lvl = 0; lvl < 2; ++lvl) {
        const int H = lvl ? 32 : 64;
        const int W = lvl ? 88 : 176;
        const int HW = H * W;
        const float* fm = lvl ? f1 : f0;

        if (t < 24) {
            int v = t >> 2, kp = t & 3;
            const float* r = refs + (size_t)(b * Q + q) * 3;
            float px = r[0] + kpx(kp), py = r[1] + kpy(kp), pz = r[2];
            const float* E = extr + (size_t)(b * V + v) * 16;
            float cx = E[0] * px + E[1] * py + E[2]  * pz + E[3];
            float cy = E[4] * px + E[5] * py + E[6]  * pz + E[7];
            float cz = E[8] * px + E[9] * py + E[10] * pz + E[11];
            const float* Km = intr + (size_t)(b * V + v) * 9;
            float u = Km[0] * cx + Km[1] * cy + Km[2] * cz;
            float w = Km[3] * cx + Km[4] * cy + Km[5] * cz;
            float z = Km[6] * cx + Km[7] * cy + Km[8] * cz;
            float zs = (fabsf(z) > 1e-6f) ? z : 1e-6f;
            float gx = 2.f * (u / zs) / (float)(W - 1) - 1.f;
            float gy = 2.f * (w / zs) / (float)(H - 1) - 1.f;
            sx[t] = (gx + 1.f) * 0.5f * (float)(W - 1);
            sy[t] = (gy + 1.f) * 0.5f * (float)(H - 1);
            sval[t] = (z > 0.f) ? 1.f : 0.f;
        }
        __syncthreads();

        float cnt = 0.f;
        #pragma unroll
        for (int i = 0; i < 24; ++i) cnt += sval[i];
        cnt = fmaxf(cnt, 1.f);

        float accl = 0.f;
        for (int i = 0; i < 24; ++i) {
            if (sval[i] == 0.f) continue;
            int v = i >> 2;
            float x = sx[i], y = sy[i];
            float x0 = floorf(x), y0 = floorf(y);
            float wx1 = x - x0, wx0 = 1.f - wx1;
            float wy1 = y - y0, wy0 = 1.f - wy1;
            const float* base = fm + ((size_t)(b * V + v) * C + t) * (size_t)HW;
            accl += tapv(base, x0,       y0,       W, H) * (wx0 * wy0)
                  + tapv(base, x0 + 1.f, y0,       W, H) * (wx1 * wy0)
                  + tapv(base, x0,       y0 + 1.f, W, H) * (wx0 * wy1)
                  + tapv(base, x0 + 1.f, y0 + 1.f, W, H) * (wx1 * wy1);
        }
        acc_total += accl / cnt;
        __syncthreads();
    }
    sampled[(size_t)(b * Q + q) * C + t] = acc_total * 0.5f;
}

// WT[k][n] = W[n][k], 256x256
__global__ __launch_bounds__(256)
void wtrans(const float* __restrict__ Wm, float* __restrict__ WT)
{
    int idx = blockIdx.x * 256 + threadIdx.x;
    int k = idx >> 8, n = idx & 255;
    WT[idx] = Wm[n * C + k];
}

// Y[m][n] = sum_k X[m][k] * WT[k][n] + bias[n]; 8 rows per block, thread = n
__global__ __launch_bounds__(256)
void gemm_bias(const float* __restrict__ X, const float* __restrict__ WT,
               const float* __restrict__ bias, float* __restrict__ Y, int M)
{
    __shared__ float xs[8][C];
    int t = threadIdx.x;
    int m0 = blockIdx.x * 8;
    #pragma unroll
    for (int r = 0; r < 8; ++r) {
        int m = m0 + r;
        xs[r][t] = (m < M) ? X[(size_t)m * C + t] : 0.f;
    }
    __syncthreads();
    float acc[8];
    float bvv = bias[t];
    #pragma unroll
    for (int r = 0; r < 8; ++r) acc[r] = bvv;
    for (int k = 0; k < C; ++k) {
        float wv = WT[(size_t)k * C + t];
        #pragma unroll
        for (int r = 0; r < 8; ++r) acc[r] += xs[r][k] * wv;
    }
    #pragma unroll
    for (int r = 0; r < 8; ++r) {
        int m = m0 + r;
        if (m < M) Y[(size_t)m * C + t] = acc[r];
    }
}

// One wave (64 lanes) per (b,h,qi) row. 4 waves per block.
__global__ __launch_bounds__(256)
void attn_kernel(const float* __restrict__ qb, const float* __restrict__ kb,
                 const float* __restrict__ vb, float* __restrict__ ob)
{
    __shared__ float sc[4][Q];   // 14.4 KB
    __shared__ float sq[4][HD];
    int t = threadIdx.x;
    int wl = t >> 6, lane = t & 63;
    int gw = blockIdx.x * 4 + wl;          // < 14400 exactly
    int b = gw / (NH * Q);
    int rem = gw % (NH * Q);
    int h = rem / Q;
    int qi = rem % Q;

    if (lane < HD) sq[wl][lane] = qb[(size_t)(b * Q + qi) * C + h * HD + lane];
    __syncthreads();

    const float scale = 0.17677669529663687f; // 1/sqrt(32)
    float mx = -INFINITY;
    for (int j = lane; j < Q; j += 64) {
        const float* kr = kb + (size_t)(b * Q + j) * C + h * HD;
        float s = 0.f;
        #pragma unroll
        for (int d = 0; d < HD; ++d) s += sq[wl][d] * kr[d];
        s *= scale;
        sc[wl][j] = s;
        mx = fmaxf(mx, s);
    }
    #pragma unroll
    for (int off = 32; off >= 1; off >>= 1) mx = fmaxf(mx, __shfl_xor(mx, off));

    float sum = 0.f;
    for (int j = lane; j < Q; j += 64) {
        float p = expf(sc[wl][j] - mx);
        sc[wl][j] = p;
        sum += p;
    }
    #pragma unroll
    for (int off = 32; off >= 1; off >>= 1) sum += __shfl_xor(sum, off);
    __syncthreads();  // make sc[] visible across lanes/waves before PV

    int d = lane & 31, half = lane >> 5;
    float acc = 0.f;
    for (int j = half; j < Q; j += 2)
        acc += sc[wl][j] * vb[(size_t)(b * Q + j) * C + h * HD + d];
    acc += __shfl_down(acc, 32);
    if (lane < 32) ob[(size_t)(b * Q + qi) * C + h * HD + lane] = acc / sum;
}

extern "C" void kernel_launch(void* const* d_in, const int* in_sizes, int n_in,
                              void* d_out, int out_size, void* d_ws, size_t ws_size,
                              hipStream_t stream) {
    const float* f0   = (const float*)d_in[0];
    const float* f1   = (const float*)d_in[1];
    const float* refs = (const float*)d_in[2];
    const float* intr = (const float*)d_in[3];
    const float* extr = (const float*)d_in[4];
    const float* qin  = (const float*)d_in[5];
    const float* Wq   = (const float*)d_in[6];
    const float* bq   = (const float*)d_in[7];
    const float* Wk   = (const float*)d_in[8];
    const float* bk   = (const float*)d_in[9];
    const float* Wv   = (const float*)d_in[10];
    const float* bv   = (const float*)d_in[11];
    const float* Wo   = (const float*)d_in[12];
    const float* bo   = (const float*)d_in[13];

    float* ws      = (float*)d_ws;
    float* sampled = ws;                  // 460800
    float* qbuf    = sampled + 460800;
    float* kbuf    = qbuf    + 460800;
    float* vbuf    = kbuf    + 460800;
    float* obuf    = vbuf    + 460800;
    float* WqT     = obuf    + 460800;    // 65536 each
    float* WkT     = WqT + 65536;
    float* WvT     = WkT + 65536;
    float* WoT     = WvT + 65536;
    float* out     = (float*)d_out;

    wtrans<<<256, 256, 0, stream>>>(Wq, WqT);
    wtrans<<<256, 256, 0, stream>>>(Wk, WkT);
    wtrans<<<256, 256, 0, stream>>>(Wv, WvT);
    wtrans<<<256, 256, 0, stream>>>(Wo, WoT);

    sampler_kernel<<<B * Q, 256, 0, stream>>>(f0, f1, refs, intr, extr, sampled);

    gemm_bias<<<225, 256, 0, stream>>>(qin,     WqT, bq, qbuf, B * Q);
    gemm_bias<<<225, 256, 0, stream>>>(sampled, WkT, bk, kbuf, B * Q);
    gemm_bias<<<225, 256, 0, stream>>>(sampled, WvT, bv, vbuf, B * Q);

    attn_kernel<<<3600, 256, 0, stream>>>(qbuf, kbuf, vbuf, obuf);

    gemm_bias<<<225, 256, 0, stream>>>(obuf, WoT, bo, out, B * Q);
}

// Round 2
// 210.414 us; speedup vs baseline: 2.1638x; 2.1638x over previous
//
#include <hip/hip_runtime.h>
#include <math.h>

#define B 2
#define V 6
#define C 256
#define Q 900
#define NH 8
#define HD 32
#define RADIUS 2.0f
#define QT 32
#define KT 64
#define NKT 15   // ceil(900/64)

// keypoints: [0,0,0],[R,0,0],[0,R,0],[-R,0,0]
__device__ __forceinline__ float kpx(int k) { return (k == 1) ? RADIUS : ((k == 3) ? -RADIUS : 0.f); }
__device__ __forceinline__ float kpy(int k) { return (k == 2) ? RADIUS : 0.f; }

__device__ __forceinline__ float tapv(const float* __restrict__ base, float xi, float yi, int W, int H) {
    if (xi < 0.f || xi > (float)(W - 1) || yi < 0.f || yi > (float)(H - 1)) return 0.f;
    int xc = (int)xi, yc = (int)yi;
    return base[yc * W + xc];
}

// One block per (b,q); thread t = channel c. 2 levels x 6 views x 4 keypoints.
__global__ __launch_bounds__(256)
void sampler_kernel(const float* __restrict__ f0, const float* __restrict__ f1,
                    const float* __restrict__ refs, const float* __restrict__ intr,
                    const float* __restrict__ extr, float* __restrict__ sampled)
{
    int b = blockIdx.x / Q, q = blockIdx.x % Q;
    int t = threadIdx.x;
    __shared__ float sx[24], sy[24], sval[24];
    float acc_total = 0.f;

    #pragma unroll
    for (int lvl = 0; lvl < 2; ++lvl) {
        const int H = lvl ? 32 : 64;
        const int W = lvl ? 88 : 176;
        const int HW = H * W;
        const float* fm = lvl ? f1 : f0;

        if (t < 24) {
            int v = t >> 2, kp = t & 3;
            const float* r = refs + (size_t)(b * Q + q) * 3;
            float px = r[0] + kpx(kp), py = r[1] + kpy(kp), pz = r[2];
            const float* E = extr + (size_t)(b * V + v) * 16;
            float cx = E[0] * px + E[1] * py + E[2]  * pz + E[3];
            float cy = E[4] * px + E[5] * py + E[6]  * pz + E[7];
            float cz = E[8] * px + E[9] * py + E[10] * pz + E[11];
            const float* Km = intr + (size_t)(b * V + v) * 9;
            float u = Km[0] * cx + Km[1] * cy + Km[2] * cz;
            float w = Km[3] * cx + Km[4] * cy + Km[5] * cz;
            float z = Km[6] * cx + Km[7] * cy + Km[8] * cz;
            float zs = (fabsf(z) > 1e-6f) ? z : 1e-6f;
            float gx = 2.f * (u / zs) / (float)(W - 1) - 1.f;
            float gy = 2.f * (w / zs) / (float)(H - 1) - 1.f;
            sx[t] = (gx + 1.f) * 0.5f * (float)(W - 1);
            sy[t] = (gy + 1.f) * 0.5f * (float)(H - 1);
            sval[t] = (z > 0.f) ? 1.f : 0.f;
        }
        __syncthreads();

        float cnt = 0.f;
        #pragma unroll
        for (int i = 0; i < 24; ++i) cnt += sval[i];
        cnt = fmaxf(cnt, 1.f);

        float accl = 0.f;
        for (int i = 0; i < 24; ++i) {
            if (sval[i] == 0.f) continue;
            int v = i >> 2;
            float x = sx[i], y = sy[i];
            float x0 = floorf(x), y0 = floorf(y);
            float wx1 = x - x0, wx0 = 1.f - wx1;
            float wy1 = y - y0, wy0 = 1.f - wy1;
            const float* base = fm + ((size_t)(b * V + v) * C + t) * (size_t)HW;
            accl += tapv(base, x0,       y0,       W, H) * (wx0 * wy0)
                  + tapv(base, x0 + 1.f, y0,       W, H) * (wx1 * wy0)
                  + tapv(base, x0,       y0 + 1.f, W, H) * (wx0 * wy1)
                  + tapv(base, x0 + 1.f, y0 + 1.f, W, H) * (wx1 * wy1);
        }
        acc_total += accl / cnt;
        __syncthreads();
    }
    sampled[(size_t)(b * Q + q) * C + t] = acc_total * 0.5f;
}

// WT[k][n] = W[n][k], 256x256
__global__ __launch_bounds__(256)
void wtrans(const float* __restrict__ Wm, float* __restrict__ WT)
{
    int idx = blockIdx.x * 256 + threadIdx.x;
    int k = idx >> 8, n = idx & 255;
    WT[idx] = Wm[n * C + k];
}

// Y[m][n] = sum_k X[m][k] * WT[k][n] + bias[n]; 8 rows per block, thread = n
__global__ __launch_bounds__(256)
void gemm_bias(const float* __restrict__ X, const float* __restrict__ WT,
               const float* __restrict__ bias, float* __restrict__ Y, int M)
{
    __shared__ float xs[8][C];
    int t = threadIdx.x;
    int m0 = blockIdx.x * 8;
    #pragma unroll
    for (int r = 0; r < 8; ++r) {
        int m = m0 + r;
        xs[r][t] = (m < M) ? X[(size_t)m * C + t] : 0.f;
    }
    __syncthreads();
    float acc[8];
    float bvv = bias[t];
    #pragma unroll
    for (int r = 0; r < 8; ++r) acc[r] = bvv;
    for (int k = 0; k < C; ++k) {
        float wv = WT[(size_t)k * C + t];
        #pragma unroll
        for (int r = 0; r < 8; ++r) acc[r] += xs[r][k] * wv;
    }
    #pragma unroll
    for (int r = 0; r < 8; ++r) {
        int m = m0 + r;
        if (m < M) Y[(size_t)m * C + t] = acc[r];
    }
}

// Fused K,V projection: shares the X tile, two weight streams.
__global__ __launch_bounds__(256)
void gemm_bias_kv(const float* __restrict__ X,
                  const float* __restrict__ WkT, const float* __restrict__ WvT,
                  const float* __restrict__ bk, const float* __restrict__ bv,
                  float* __restrict__ Yk, float* __restrict__ Yv, int M)
{
    __shared__ float xs[8][C];
    int t = threadIdx.x;
    int m0 = blockIdx.x * 8;
    #pragma unroll
    for (int r = 0; r < 8; ++r) {
        int m = m0 + r;
        xs[r][t] = (m < M) ? X[(size_t)m * C + t] : 0.f;
    }
    __syncthreads();
    float ak[8], av[8];
    float bkv = bk[t], bvv = bv[t];
    #pragma unroll
    for (int r = 0; r < 8; ++r) { ak[r] = bkv; av[r] = bvv; }
    for (int k = 0; k < C; ++k) {
        float wk = WkT[(size_t)k * C + t];
        float wv = WvT[(size_t)k * C + t];
        #pragma unroll
        for (int r = 0; r < 8; ++r) {
            float x = xs[r][k];
            ak[r] += x * wk;
            av[r] += x * wv;
        }
    }
    #pragma unroll
    for (int r = 0; r < 8; ++r) {
        int m = m0 + r;
        if (m < M) {
            Yk[(size_t)m * C + t] = ak[r];
            Yv[(size_t)m * C + t] = av[r];
        }
    }
}

// Flash-style attention: block = (b, h, q-tile of 32). 256 threads.
// Thread (ty,tx): ty=tid/16 -> q rows {2ty, 2ty+1}; tx=tid%16.
// QK phase: thread owns keys {4tx..4tx+3} -> s[2][4].
// PV phase: thread owns dims {2tx, 2tx+1}  -> acc[2][2].
// LDS swizzles chosen per-array for conflict-free ds_read_b128 on the hot reads.
__global__ __launch_bounds__(256)
void attn_flash(const float* __restrict__ qb, const float* __restrict__ kb,
                const float* __restrict__ vb, float* __restrict__ ob)
{
    __shared__ float Qs[QT * 32];      // (r,d): r*32 + (d ^ ((r&7)<<2))
    __shared__ float Ks[KT * 32];      // (r,d): r*32 + (d ^ (((r>>2)&7)<<2))
    __shared__ float Vs[KT * 32];      // (r,d): r*32 + d  (read pattern already conflict-free)
    __shared__ float Ps[4 * 8 * 64];   // per-wave: wl*512 + r*64 + (k ^ ((r&7)<<2))

    const int tid = threadIdx.x;
    const int ty = tid >> 4;          // 0..15
    const int tx = tid & 15;          // 0..15
    const int wl = tid >> 6;          // wave 0..3
    const int b = blockIdx.z, h = blockIdx.y, qt = blockIdx.x;
    const int q0 = qt * QT;

    // ---- stage Q (pre-scaled by 1/sqrt(hd)) ----
    {
        const float sc = 0.17677669529663687f;
        int r = tid >> 3, dc = (tid & 7) << 2;
        int qi = q0 + r;
        float4 qv = make_float4(0.f, 0.f, 0.f, 0.f);
        if (qi < Q) qv = *(const float4*)(qb + (size_t)(b * Q + qi) * C + h * HD + dc);
        float* dst = &Qs[r * 32 + (dc ^ ((r & 7) << 2))];
        dst[0] = qv.x * sc; dst[1] = qv.y * sc; dst[2] = qv.z * sc; dst[3] = qv.w * sc;
    }

    float m_[2] = { -1e30f, -1e30f };
    float l_[2] = { 0.f, 0.f };
    float acc[2][2] = { {0.f, 0.f}, {0.f, 0.f} };

    const int rA = 2 * ty, rB = rA + 1;            // global q rows within tile (0..31)
    const int rlA = 2 * (ty & 3), rlB = rlA + 1;   // wave-local P rows (0..7)
    float* Pw = &Ps[wl * 512];
    const int swzA = (rA & 7) << 2, swzB = (rB & 7) << 2;
    const int kswz = (tx & 7) << 2;                // (kr>>2)&7 == tx for kr=4tx+j

    for (int kt = 0; kt < NKT; ++kt) {
        const int k0 = kt * KT;
        __syncthreads();   // previous tile's readers done before restaging

        // ---- stage K, V (coalesced float4) ----
        #pragma unroll
        for (int h2 = 0; h2 < 2; ++h2) {
            int r = (tid >> 3) + h2 * 32;
            int dc = (tid & 7) << 2;
            int ki = k0 + r;
            float4 kv = make_float4(0.f, 0.f, 0.f, 0.f);
            float4 vv = make_float4(0.f, 0.f, 0.f, 0.f);
            if (ki < Q) {
                kv = *(const float4*)(kb + (size_t)(b * Q + ki) * C + h * HD + dc);
                vv = *(const float4*)(vb + (size_t)(b * Q + ki) * C + h * HD + dc);
            }
            *(float4*)(&Ks[r * 32 + (dc ^ (((r >> 2) & 7) << 2))]) = kv;
            *(float4*)(&Vs[r * 32 + dc]) = vv;
        }
        __syncthreads();

        // ---- QK^T: s[2][4] ----
        float s[2][4] = { {0.f,0.f,0.f,0.f}, {0.f,0.f,0.f,0.f} };
        #pragma unroll
        for (int dc = 0; dc < 32; dc += 4) {
            float4 qv0 = *(const float4*)(&Qs[rA * 32 + (dc ^ swzA)]);
            float4 qv1 = *(const float4*)(&Qs[rB * 32 + (dc ^ swzB)]);
            #pragma unroll
            for (int j = 0; j < 4; ++j) {
                float4 kv = *(const float4*)(&Ks[(4 * tx + j) * 32 + (dc ^ kswz)]);
                s[0][j] += qv0.x * kv.x + qv0.y * kv.y + qv0.z * kv.z + qv0.w * kv.w;
                s[1][j] += qv1.x * kv.x + qv1.y * kv.y + qv1.z * kv.z + qv1.w * kv.w;
            }
        }
        // mask invalid keys
        #pragma unroll
        for (int j = 0; j < 4; ++j) {
            if (k0 + 4 * tx + j >= Q) { s[0][j] = -1e30f; s[1][j] = -1e30f; }
        }

        // ---- online softmax (row = 16 consecutive lanes) ----
        #pragma unroll
        for (int i = 0; i < 2; ++i) {
            float tm = fmaxf(fmaxf(s[i][0], s[i][1]), fmaxf(s[i][2], s[i][3]));
            #pragma unroll
            for (int o = 1; o < 16; o <<= 1) tm = fmaxf(tm, __shfl_xor(tm, o));
            float mn = fmaxf(m_[i], tm);
            float al = __expf(m_[i] - mn);
            float ps = 0.f;
            #pragma unroll
            for (int j = 0; j < 4; ++j) { float p = __expf(s[i][j] - mn); s[i][j] = p; ps += p; }
            #pragma unroll
            for (int o = 1; o < 16; o <<= 1) ps += __shfl_xor(ps, o);
            l_[i] = l_[i] * al + ps;
            m_[i] = mn;
            acc[i][0] *= al; acc[i][1] *= al;
        }

        // ---- P -> LDS (wave-private region) ----
        *(float4*)(&Pw[rlA * 64 + ((4 * tx) ^ (rlA << 2))]) = make_float4(s[0][0], s[0][1], s[0][2], s[0][3]);
        *(float4*)(&Pw[rlB * 64 + ((4 * tx) ^ (rlB << 2))]) = make_float4(s[1][0], s[1][1], s[1][2], s[1][3]);
        __syncthreads();

        // ---- PV: acc[2][2], d = 2*tx + {0,1} ----
        #pragma unroll 4
        for (int kc = 0; kc < 16; ++kc) {
            int kk = kc << 2;
            float4 pA = *(const float4*)(&Pw[rlA * 64 + (kk ^ (rlA << 2))]);
            float4 pB = *(const float4*)(&Pw[rlB * 64 + (kk ^ (rlB << 2))]);
            float2 v0 = *(const float2*)(&Vs[(kk + 0) * 32 + 2 * tx]);
            float2 v1 = *(const float2*)(&Vs[(kk + 1) * 32 + 2 * tx]);
            float2 v2 = *(const float2*)(&Vs[(kk + 2) * 32 + 2 * tx]);
            float2 v3 = *(const float2*)(&Vs[(kk + 3) * 32 + 2 * tx]);
            acc[0][0] += pA.x * v0.x; acc[0][1] += pA.x * v0.y;
            acc[1][0] += pB.x * v0.x; acc[1][1] += pB.x * v0.y;
            acc[0][0] += pA.y * v1.x; acc[0][1] += pA.y * v1.y;
            acc[1][0] += pB.y * v1.x; acc[1][1] += pB.y * v1.y;
            acc[0][0] += pA.z * v2.x; acc[0][1] += pA.z * v2.y;
            acc[1][0] += pB.z * v2.x; acc[1][1] += pB.z * v2.y;
            acc[0][0] += pA.w * v3.x; acc[0][1] += pA.w * v3.y;
            acc[1][0] += pB.w * v3.x; acc[1][1] += pB.w * v3.y;
        }
    }

    // ---- write out ----
    {
        int qrow = q0 + rA;
        if (qrow < Q) {
            float inv = 1.f / l_[0];
            float2 o; o.x = acc[0][0] * inv; o.y = acc[0][1] * inv;
            *(float2*)(ob + (size_t)(b * Q + qrow) * C + h * HD + 2 * tx) = o;
        }
        qrow = q0 + rB;
        if (qrow < Q) {
            float inv = 1.f / l_[1];
            float2 o; o.x = acc[1][0] * inv; o.y = acc[1][1] * inv;
            *(float2*)(ob + (size_t)(b * Q + qrow) * C + h * HD + 2 * tx) = o;
        }
    }
}

extern "C" void kernel_launch(void* const* d_in, const int* in_sizes, int n_in,
                              void* d_out, int out_size, void* d_ws, size_t ws_size,
                              hipStream_t stream) {
    const float* f0   = (const float*)d_in[0];
    const float* f1   = (const float*)d_in[1];
    const float* refs = (const float*)d_in[2];
    const float* intr = (const float*)d_in[3];
    const float* extr = (const float*)d_in[4];
    const float* qin  = (const float*)d_in[5];
    const float* Wq   = (const float*)d_in[6];
    const float* bq   = (const float*)d_in[7];
    const float* Wk   = (const float*)d_in[8];
    const float* bk   = (const float*)d_in[9];
    const float* Wv   = (const float*)d_in[10];
    const float* bv   = (const float*)d_in[11];
    const float* Wo   = (const float*)d_in[12];
    const float* bo   = (const float*)d_in[13];

    float* ws      = (float*)d_ws;
    float* sampled = ws;                  // 460800
    float* qbuf    = sampled + 460800;
    float* kbuf    = qbuf    + 460800;
    float* vbuf    = kbuf    + 460800;
    float* obuf    = vbuf    + 460800;
    float* WqT     = obuf    + 460800;    // 65536 each
    float* WkT     = WqT + 65536;
    float* WvT     = WkT + 65536;
    float* WoT     = WvT + 65536;
    float* out     = (float*)d_out;

    wtrans<<<256, 256, 0, stream>>>(Wq, WqT);
    wtrans<<<256, 256, 0, stream>>>(Wk, WkT);
    wtrans<<<256, 256, 0, stream>>>(Wv, WvT);
    wtrans<<<256, 256, 0, stream>>>(Wo, WoT);

    sampler_kernel<<<B * Q, 256, 0, stream>>>(f0, f1, refs, intr, extr, sampled);

    gemm_bias<<<225, 256, 0, stream>>>(qin, WqT, bq, qbuf, B * Q);
    gemm_bias_kv<<<225, 256, 0, stream>>>(sampled, WkT, WvT, bk, bv, kbuf, vbuf, B * Q);

    dim3 agrid((Q + QT - 1) / QT, NH, B);
    attn_flash<<<agrid, 256, 0, stream>>>(qbuf, kbuf, vbuf, obuf);

    gemm_bias<<<225, 256, 0, stream>>>(obuf, WoT, bo, out, B * Q);
}

// Round 3
// 134.712 us; speedup vs baseline: 3.3798x; 1.5620x over previous
//
#include <hip/hip_runtime.h>
#include <math.h>

#define B 2
#define V 6
#define C 256
#define Q 900
#define NH 8
#define HD 32
#define RADIUS 2.0f
#define QT 32
#define KT 64
#define NKT 15   // ceil(900/64)
#define M_ROWS (B * Q)   // 1800

// keypoints: [0,0,0],[R,0,0],[0,R,0],[-R,0,0]
__device__ __forceinline__ float kpx(int k) { return (k == 1) ? RADIUS : ((k == 3) ? -RADIUS : 0.f); }
__device__ __forceinline__ float kpy(int k) { return (k == 2) ? RADIUS : 0.f; }

__device__ __forceinline__ float tapv(const float* __restrict__ base, float xi, float yi, int W, int H) {
    if (xi < 0.f || xi > (float)(W - 1) || yi < 0.f || yi > (float)(H - 1)) return 0.f;
    int xc = (int)xi, yc = (int)yi;
    return base[yc * W + xc];
}

// One block per (b,q); thread t = channel c. 2 levels x 6 views x 4 keypoints.
__global__ __launch_bounds__(256)
void sampler_kernel(const float* __restrict__ f0, const float* __restrict__ f1,
                    const float* __restrict__ refs, const float* __restrict__ intr,
                    const float* __restrict__ extr, float* __restrict__ sampled)
{
    int b = blockIdx.x / Q, q = blockIdx.x % Q;
    int t = threadIdx.x;
    __shared__ float sx[24], sy[24], sval[24];
    float acc_total = 0.f;

    #pragma unroll
    for (int lvl = 0; lvl < 2; ++lvl) {
        const int H = lvl ? 32 : 64;
        const int W = lvl ? 88 : 176;
        const int HW = H * W;
        const float* fm = lvl ? f1 : f0;

        if (t < 24) {
            int v = t >> 2, kp = t & 3;
            const float* r = refs + (size_t)(b * Q + q) * 3;
            float px = r[0] + kpx(kp), py = r[1] + kpy(kp), pz = r[2];
            const float* E = extr + (size_t)(b * V + v) * 16;
            float cx = E[0] * px + E[1] * py + E[2]  * pz + E[3];
            float cy = E[4] * px + E[5] * py + E[6]  * pz + E[7];
            float cz = E[8] * px + E[9] * py + E[10] * pz + E[11];
            const float* Km = intr + (size_t)(b * V + v) * 9;
            float u = Km[0] * cx + Km[1] * cy + Km[2] * cz;
            float w = Km[3] * cx + Km[4] * cy + Km[5] * cz;
            float z = Km[6] * cx + Km[7] * cy + Km[8] * cz;
            float zs = (fabsf(z) > 1e-6f) ? z : 1e-6f;
            float gx = 2.f * (u / zs) / (float)(W - 1) - 1.f;
            float gy = 2.f * (w / zs) / (float)(H - 1) - 1.f;
            sx[t] = (gx + 1.f) * 0.5f * (float)(W - 1);
            sy[t] = (gy + 1.f) * 0.5f * (float)(H - 1);
            sval[t] = (z > 0.f) ? 1.f : 0.f;
        }
        __syncthreads();

        float cnt = 0.f;
        #pragma unroll
        for (int i = 0; i < 24; ++i) cnt += sval[i];
        cnt = fmaxf(cnt, 1.f);

        float accl = 0.f;
        for (int i = 0; i < 24; ++i) {
            if (sval[i] == 0.f) continue;
            int v = i >> 2;
            float x = sx[i], y = sy[i];
            float x0 = floorf(x), y0 = floorf(y);
            float wx1 = x - x0, wx0 = 1.f - wx1;
            float wy1 = y - y0, wy0 = 1.f - wy1;
            const float* base = fm + ((size_t)(b * V + v) * C + t) * (size_t)HW;
            accl += tapv(base, x0,       y0,       W, H) * (wx0 * wy0)
                  + tapv(base, x0 + 1.f, y0,       W, H) * (wx1 * wy0)
                  + tapv(base, x0,       y0 + 1.f, W, H) * (wx0 * wy1)
                  + tapv(base, x0 + 1.f, y0 + 1.f, W, H) * (wx1 * wy1);
        }
        acc_total += accl / cnt;
        __syncthreads();
    }
    sampled[(size_t)(b * Q + q) * C + t] = acc_total * 0.5f;
}

// Fused transpose of 4 weight mats, LDS-tiled, coalesced both sides.
// grid = 4 mats * 64 tiles; WT[k][n] = W[n][k].
__global__ __launch_bounds__(256)
void wtrans4(const float* __restrict__ W0, const float* __restrict__ W1,
             const float* __restrict__ W2, const float* __restrict__ W3,
             float* __restrict__ T0, float* __restrict__ T1,
             float* __restrict__ T2, float* __restrict__ T3)
{
    __shared__ float tile[32][33];
    int mat = blockIdx.x >> 6, tpos = blockIdx.x & 63;
    const float* src = (mat == 0) ? W0 : (mat == 1) ? W1 : (mat == 2) ? W2 : W3;
    float* dst = (mat == 0) ? T0 : (mat == 1) ? T1 : (mat == 2) ? T2 : T3;
    int bx = (tpos & 7) * 32, by = (tpos >> 3) * 32;   // src: rows by.., cols bx..
    int r0 = threadIdx.x >> 5, cc = threadIdx.x & 31;
    #pragma unroll
    for (int i = 0; i < 4; ++i) {
        int r = r0 + 8 * i;
        tile[r][cc] = src[(size_t)(by + r) * C + bx + cc];
    }
    __syncthreads();
    #pragma unroll
    for (int i = 0; i < 4; ++i) {
        int r = r0 + 8 * i;
        dst[(size_t)(bx + r) * C + by + cc] = tile[cc][r];
    }
}

// Tiled fp32 GEMM: Y[m][n] = sum_k A[m][k] * Wt[k][n] + bias[n].
// BM=BN=64, BK=32, 256 threads, 4x4 micro-tile.
__device__ __forceinline__ void gemm_body(const float* __restrict__ A,
                                          const float* __restrict__ Wt,
                                          const float* __restrict__ bias,
                                          float* __restrict__ Y,
                                          int m0, int n0)
{
    __shared__ float As[32][64];   // k-major
    __shared__ float Bs[32][64];
    const int t = threadIdx.x;
    const int tx = t & 15, ty = t >> 4;
    const int mm = 4 * tx;           // micro m within tile
    const int nn = 4 * ty;           // micro n within tile

    float acc[4][4];
    {
        float4 bv4 = *(const float4*)(bias + n0 + nn);
        #pragma unroll
        for (int i = 0; i < 4; ++i) {
            acc[i][0] = bv4.x; acc[i][1] = bv4.y; acc[i][2] = bv4.z; acc[i][3] = bv4.w;
        }
    }

    const int am = t & 63;           // A staging row (m within tile)
    const int af = t >> 6;           // float4 index base (0..3)

    for (int ks = 0; ks < C; ks += 32) {
        __syncthreads();
        // stage A (k-major): As[k][m]
        #pragma unroll
        for (int i = 0; i < 2; ++i) {
            int f = af + 4 * i;                  // 0..7
            int gm = m0 + am;
            float4 v = make_float4(0.f, 0.f, 0.f, 0.f);
            if (gm < M_ROWS) v = *(const float4*)(A + (size_t)gm * C + ks + 4 * f);
            As[4 * f + 0][am] = v.x;
            As[4 * f + 1][am] = v.y;
            As[4 * f + 2][am] = v.z;
            As[4 * f + 3][am] = v.w;
        }
        // stage B: Bs[k][n]
        #pragma unroll
        for (int i = 0; i < 2; ++i) {
            int idx = t + 256 * i;
            int kr = idx >> 4, nf = idx & 15;
            float4 v = *(const float4*)(Wt + (size_t)(ks + kr) * C + n0 + 4 * nf);
            *(float4*)(&Bs[kr][4 * nf]) = v;
        }
        __syncthreads();

        #pragma unroll
        for (int kk = 0; kk < 32; ++kk) {
            float4 a = *(const float4*)(&As[kk][mm]);
            float4 b = *(const float4*)(&Bs[kk][nn]);
            acc[0][0] += a.x * b.x; acc[0][1] += a.x * b.y; acc[0][2] += a.x * b.z; acc[0][3] += a.x * b.w;
            acc[1][0] += a.y * b.x; acc[1][1] += a.y * b.y; acc[1][2] += a.y * b.z; acc[1][3] += a.y * b.w;
            acc[2][0] += a.z * b.x; acc[2][1] += a.z * b.y; acc[2][2] += a.z * b.z; acc[2][3] += a.z * b.w;
            acc[3][0] += a.w * b.x; acc[3][1] += a.w * b.y; acc[3][2] += a.w * b.z; acc[3][3] += a.w * b.w;
        }
    }

    #pragma unroll
    for (int i = 0; i < 4; ++i) {
        int gm = m0 + mm + i;
        if (gm < M_ROWS) {
            *(float4*)(Y + (size_t)gm * C + n0 + nn) =
                make_float4(acc[i][0], acc[i][1], acc[i][2], acc[i][3]);
        }
    }
}

// Fused Q/K/V projections: z selects {A, W, bias, Y}.
__global__ __launch_bounds__(256)
void gemm_qkv(const float* __restrict__ Xq, const float* __restrict__ Xs,
              const float* __restrict__ WqT, const float* __restrict__ WkT,
              const float* __restrict__ WvT,
              const float* __restrict__ bq, const float* __restrict__ bk,
              const float* __restrict__ bv,
              float* __restrict__ Yq, float* __restrict__ Yk, float* __restrict__ Yv)
{
    int z = blockIdx.z;
    const float* A    = (z == 0) ? Xq  : Xs;
    const float* Wt   = (z == 0) ? WqT : (z == 1) ? WkT : WvT;
    const float* bias = (z == 0) ? bq  : (z == 1) ? bk  : bv;
    float* Y          = (z == 0) ? Yq  : (z == 1) ? Yk  : Yv;
    gemm_body(A, Wt, bias, Y, blockIdx.x * 64, blockIdx.y * 64);
}

__global__ __launch_bounds__(256)
void gemm_one(const float* __restrict__ A, const float* __restrict__ Wt,
              const float* __restrict__ bias, float* __restrict__ Y)
{
    gemm_body(A, Wt, bias, Y, blockIdx.x * 64, blockIdx.y * 64);
}

// Flash-style attention: block = (b, h, q-tile of 32). 256 threads.
__global__ __launch_bounds__(256)
void attn_flash(const float* __restrict__ qb, const float* __restrict__ kb,
                const float* __restrict__ vb, float* __restrict__ ob)
{
    __shared__ float Qs[QT * 32];      // (r,d): r*32 + (d ^ ((r&7)<<2))
    __shared__ float Ks[KT * 32];      // (r,d): r*32 + (d ^ (((r>>2)&7)<<2))
    __shared__ float Vs[KT * 32];      // (r,d): r*32 + d
    __shared__ float Ps[4 * 8 * 64];   // per-wave: wl*512 + r*64 + (k ^ ((r&7)<<2))

    const int tid = threadIdx.x;
    const int ty = tid >> 4;          // 0..15
    const int tx = tid & 15;          // 0..15
    const int wl = tid >> 6;          // wave 0..3
    const int b = blockIdx.z, h = blockIdx.y, qt = blockIdx.x;
    const int q0 = qt * QT;

    {
        const float sc = 0.17677669529663687f;
        int r = tid >> 3, dc = (tid & 7) << 2;
        int qi = q0 + r;
        float4 qv = make_float4(0.f, 0.f, 0.f, 0.f);
        if (qi < Q) qv = *(const float4*)(qb + (size_t)(b * Q + qi) * C + h * HD + dc);
        float* dst = &Qs[r * 32 + (dc ^ ((r & 7) << 2))];
        dst[0] = qv.x * sc; dst[1] = qv.y * sc; dst[2] = qv.z * sc; dst[3] = qv.w * sc;
    }

    float m_[2] = { -1e30f, -1e30f };
    float l_[2] = { 0.f, 0.f };
    float acc[2][2] = { {0.f, 0.f}, {0.f, 0.f} };

    const int rA = 2 * ty, rB = rA + 1;
    const int rlA = 2 * (ty & 3), rlB = rlA + 1;
    float* Pw = &Ps[wl * 512];
    const int swzA = (rA & 7) << 2, swzB = (rB & 7) << 2;
    const int kswz = (tx & 7) << 2;

    for (int kt = 0; kt < NKT; ++kt) {
        const int k0 = kt * KT;
        __syncthreads();

        #pragma unroll
        for (int h2 = 0; h2 < 2; ++h2) {
            int r = (tid >> 3) + h2 * 32;
            int dc = (tid & 7) << 2;
            int ki = k0 + r;
            float4 kv = make_float4(0.f, 0.f, 0.f, 0.f);
            float4 vv = make_float4(0.f, 0.f, 0.f, 0.f);
            if (ki < Q) {
                kv = *(const float4*)(kb + (size_t)(b * Q + ki) * C + h * HD + dc);
                vv = *(const float4*)(vb + (size_t)(b * Q + ki) * C + h * HD + dc);
            }
            *(float4*)(&Ks[r * 32 + (dc ^ (((r >> 2) & 7) << 2))]) = kv;
            *(float4*)(&Vs[r * 32 + dc]) = vv;
        }
        __syncthreads();

        float s[2][4] = { {0.f,0.f,0.f,0.f}, {0.f,0.f,0.f,0.f} };
        #pragma unroll
        for (int dc = 0; dc < 32; dc += 4) {
            float4 qv0 = *(const float4*)(&Qs[rA * 32 + (dc ^ swzA)]);
            float4 qv1 = *(const float4*)(&Qs[rB * 32 + (dc ^ swzB)]);
            #pragma unroll
            for (int j = 0; j < 4; ++j) {
                float4 kv = *(const float4*)(&Ks[(4 * tx + j) * 32 + (dc ^ kswz)]);
                s[0][j] += qv0.x * kv.x + qv0.y * kv.y + qv0.z * kv.z + qv0.w * kv.w;
                s[1][j] += qv1.x * kv.x + qv1.y * kv.y + qv1.z * kv.z + qv1.w * kv.w;
            }
        }
        #pragma unroll
        for (int j = 0; j < 4; ++j) {
            if (k0 + 4 * tx + j >= Q) { s[0][j] = -1e30f; s[1][j] = -1e30f; }
        }

        #pragma unroll
        for (int i = 0; i < 2; ++i) {
            float tm = fmaxf(fmaxf(s[i][0], s[i][1]), fmaxf(s[i][2], s[i][3]));
            #pragma unroll
            for (int o = 1; o < 16; o <<= 1) tm = fmaxf(tm, __shfl_xor(tm, o));
            float mn = fmaxf(m_[i], tm);
            float al = __expf(m_[i] - mn);
            float ps = 0.f;
            #pragma unroll
            for (int j = 0; j < 4; ++j) { float p = __expf(s[i][j] - mn); s[i][j] = p; ps += p; }
            #pragma unroll
            for (int o = 1; o < 16; o <<= 1) ps += __shfl_xor(ps, o);
            l_[i] = l_[i] * al + ps;
            m_[i] = mn;
            acc[i][0] *= al; acc[i][1] *= al;
        }

        *(float4*)(&Pw[rlA * 64 + ((4 * tx) ^ (rlA << 2))]) = make_float4(s[0][0], s[0][1], s[0][2], s[0][3]);
        *(float4*)(&Pw[rlB * 64 + ((4 * tx) ^ (rlB << 2))]) = make_float4(s[1][0], s[1][1], s[1][2], s[1][3]);
        __syncthreads();

        #pragma unroll 4
        for (int kc = 0; kc < 16; ++kc) {
            int kk = kc << 2;
            float4 pA = *(const float4*)(&Pw[rlA * 64 + (kk ^ (rlA << 2))]);
            float4 pB = *(const float4*)(&Pw[rlB * 64 + (kk ^ (rlB << 2))]);
            float2 v0 = *(const float2*)(&Vs[(kk + 0) * 32 + 2 * tx]);
            float2 v1 = *(const float2*)(&Vs[(kk + 1) * 32 + 2 * tx]);
            float2 v2 = *(const float2*)(&Vs[(kk + 2) * 32 + 2 * tx]);
            float2 v3 = *(const float2*)(&Vs[(kk + 3) * 32 + 2 * tx]);
            acc[0][0] += pA.x * v0.x; acc[0][1] += pA.x * v0.y;
            acc[1][0] += pB.x * v0.x; acc[1][1] += pB.x * v0.y;
            acc[0][0] += pA.y * v1.x; acc[0][1] += pA.y * v1.y;
            acc[1][0] += pB.y * v1.x; acc[1][1] += pB.y * v1.y;
            acc[0][0] += pA.z * v2.x; acc[0][1] += pA.z * v2.y;
            acc[1][0] += pB.z * v2.x; acc[1][1] += pB.z * v2.y;
            acc[0][0] += pA.w * v3.x; acc[0][1] += pA.w * v3.y;
            acc[1][0] += pB.w * v3.x; acc[1][1] += pB.w * v3.y;
        }
    }

    {
        int qrow = q0 + rA;
        if (qrow < Q) {
            float inv = 1.f / l_[0];
            float2 o; o.x = acc[0][0] * inv; o.y = acc[0][1] * inv;
            *(float2*)(ob + (size_t)(b * Q + qrow) * C + h * HD + 2 * tx) = o;
        }
        qrow = q0 + rB;
        if (qrow < Q) {
            float inv = 1.f / l_[1];
            float2 o; o.x = acc[1][0] * inv; o.y = acc[1][1] * inv;
            *(float2*)(ob + (size_t)(b * Q + qrow) * C + h * HD + 2 * tx) = o;
        }
    }
}

extern "C" void kernel_launch(void* const* d_in, const int* in_sizes, int n_in,
                              void* d_out, int out_size, void* d_ws, size_t ws_size,
                              hipStream_t stream) {
    const float* f0   = (const float*)d_in[0];
    const float* f1   = (const float*)d_in[1];
    const float* refs = (const float*)d_in[2];
    const float* intr = (const float*)d_in[3];
    const float* extr = (const float*)d_in[4];
    const float* qin  = (const float*)d_in[5];
    const float* Wq   = (const float*)d_in[6];
    const float* bq   = (const float*)d_in[7];
    const float* Wk   = (const float*)d_in[8];
    const float* bk   = (const float*)d_in[9];
    const float* Wv   = (const float*)d_in[10];
    const float* bv   = (const float*)d_in[11];
    const float* Wo   = (const float*)d_in[12];
    const float* bo   = (const float*)d_in[13];

    float* ws      = (float*)d_ws;
    float* sampled = ws;                  // 460800
    float* qbuf    = sampled + 460800;
    float* kbuf    = qbuf    + 460800;
    float* vbuf    = kbuf    + 460800;
    float* obuf    = vbuf    + 460800;
    float* WqT     = obuf    + 460800;    // 65536 each
    float* WkT     = WqT + 65536;
    float* WvT     = WkT + 65536;
    float* WoT     = WvT + 65536;
    float* out     = (float*)d_out;

    wtrans4<<<256, 256, 0, stream>>>(Wq, Wk, Wv, Wo, WqT, WkT, WvT, WoT);

    sampler_kernel<<<B * Q, 256, 0, stream>>>(f0, f1, refs, intr, extr, sampled);

    dim3 ggrid((M_ROWS + 63) / 64, C / 64, 3);
    gemm_qkv<<<ggrid, 256, 0, stream>>>(qin, sampled, WqT, WkT, WvT,
                                        bq, bk, bv, qbuf, kbuf, vbuf);

    dim3 agrid((Q + QT - 1) / QT, NH, B);
    attn_flash<<<agrid, 256, 0, stream>>>(qbuf, kbuf, vbuf, obuf);

    dim3 ogrid((M_ROWS + 63) / 64, C / 64, 1);
    gemm_one<<<ogrid, 256, 0, stream>>>(obuf, WoT, bo, out);
}